// Round 6
// baseline (467.308 us; speedup 1.0000x reference)
//
#include <hip/hip_runtime.h>
#include <hip/hip_fp16.h>
#include <hip/hip_cooperative_groups.h>

namespace cg = cooperative_groups;

#define B_    4
#define CIN_  64
#define COUT_ 64
#define N_    16384
#define K_    8

#define EDGES_PER_B (K_ * N_)            // 131072
#define TOT_EDGES   (B_ * EDGES_PER_B)   // 524288

#define FB 512   // fused grid blocks
#define FT 512   // fused block threads

struct h4 { __half2 lo, hi; };   // 8 B

// ===========================================================================
// FUSED PATH: one cooperative kernel = zero+hist+scan+rec+contrib+gather.
// Phase bodies are byte-identical to the round-5 verified kernels.
// 512 blocks x 512 threads, 80 KiB LDS -> exactly 2 blocks/CU x 256 CU.
// ===========================================================================
__global__ __launch_bounds__(512, 4) void fc_fused(
    const float*  __restrict__ feat,     // [B, CIN, N]
    const float*  __restrict__ theta,    // [3, CIN, COUT]
    const float*  __restrict__ wbias,    // [CIN, COUT]
    const int*    __restrict__ nbh,      // [B, K, N]
    const float*  __restrict__ pos,      // [B, 3, N]
    const float*  __restrict__ bias,     // [COUT]
    float*        __restrict__ out,      // [B, COUT, N]
    __half*       __restrict__ contrib,  // [B, K*N, COUT]
    int*          __restrict__ offsets,  // [B, N]
    int*          __restrict__ counts,   // [B, N]
    int*          __restrict__ cursor,   // [B, N]
    float4*       __restrict__ rec)      // [B, N, K] {qx,qy,qz,slot}
{
    __shared__ float4 Wl[CIN_ * COUT_];   // 64 KiB (contrib W; gather T/V alias)
    __shared__ float  Fl[CIN_ * 64];      // 16 KiB (contrib F; scan s[] alias)

    cg::grid_group grid = cg::this_grid();

    const int tid = threadIdx.x;
    const int blk = blockIdx.x;
    const int gid = blk * FT + tid;

    // ---- phase 0: zero counts --------------------------------------------
    if (gid < B_ * N_) counts[gid] = 0;
    grid.sync();

    // ---- phase 1: histogram (TOT_EDGES = 2 * FB*FT exactly) --------------
    #pragma unroll
    for (int r = 0; r < 2; ++r) {
        const int e = gid + r * (FB * FT);
        const int b = e / EDGES_PER_B;
        atomicAdd(&counts[b * N_ + nbh[e]], 1);
    }
    grid.sync();

    // ---- phase 2: per-batch exclusive scan (blocks 0..3) -----------------
    if (blk < B_) {
        int* s = (int*)Fl;                  // 2 KiB of Fl
        const int base = blk * N_ + tid * 32;
        int sum = 0;
        #pragma unroll
        for (int q = 0; q < 32; ++q) sum += counts[base + q];
        s[tid] = sum;
        __syncthreads();
        for (int d = 1; d < 512; d <<= 1) {
            const int v = (tid >= d) ? s[tid - d] : 0;
            __syncthreads();
            s[tid] += v;
            __syncthreads();
        }
        int off = s[tid] - sum;             // exclusive base for this chunk
        #pragma unroll
        for (int q = 0; q < 32; ++q) {
            const int c = counts[base + q];
            offsets[base + q] = off;
            cursor [base + q] = off;
            off += c;
        }
    }
    grid.sync();

    // ---- phase 3: per-edge records {pos_j, slot} -------------------------
    if (gid < B_ * N_) {
        const int b = gid >> 14;            // / N_
        const int n = gid & (N_ - 1);
        const int*   nbhb = nbh + (size_t)b * K_ * N_;
        const float* posb = pos + (size_t)b * 3 * N_;
        float4*      recb = rec + ((size_t)b * N_ + n) * K_;
        #pragma unroll
        for (int k = 0; k < K_; ++k) {
            const int j    = nbhb[k * N_ + n];                   // coalesced
            const int slot = atomicAdd(&cursor[b * N_ + j], 1);  // L2-resident
            recb[k] = make_float4(posb[j], posb[N_ + j], posb[2 * N_ + j],
                                  __int_as_float(slot));
        }
    }
    grid.sync();

    // ---- phase 4: contrib (identical mapping: 512 blocks, 128 pts each) --
    {
        const int lane = tid & 63;          // o
        const int w    = tid >> 6;          // wave 0..7
        const int b     = blk >> 7;         // / 128
        const int nbase = (blk & 127) * 128;

        for (int e = tid; e < CIN_ * COUT_; e += FT) {
            const int i = e >> 6, o = e & 63;
            float4 wv;
            wv.x = theta[0 * CIN_ * COUT_ + i * COUT_ + o];
            wv.y = theta[1 * CIN_ * COUT_ + i * COUT_ + o];
            wv.z = theta[2 * CIN_ * COUT_ + i * COUT_ + o];
            wv.w = wbias[i * COUT_ + o];
            Wl[e] = wv;
        }

        const float*  featb = feat + (size_t)b * CIN_ * N_;
        const float*  posb  = pos  + (size_t)b * 3 * N_;
        const float4* recb  = rec  + (size_t)b * N_ * K_;
        __half*       cb    = contrib + ((size_t)b * EDGES_PER_B << 6);

        for (int t = 0; t < 2; ++t) {
            const int n0 = nbase + t * 64;

            __syncthreads();   // Wl ready (t=0) / previous Fl readers done
            for (int r = 0; r < 8; ++r) {
                const int i = r * 8 + w;
                Fl[i * 64 + lane] = featb[(size_t)i * N_ + n0 + lane];
            }
            __syncthreads();

            const int nn = w * 8;
            float4 acc[8];
            #pragma unroll
            for (int j = 0; j < 8; ++j) acc[j] = make_float4(0.f, 0.f, 0.f, 0.f);

            #pragma unroll 2
            for (int i = 0; i < CIN_; ++i) {
                const float4 wv = Wl[i * 64 + lane];              // b128, conflict-free
                const float4 fA = *(const float4*)&Fl[i * 64 + nn];     // broadcast
                const float4 fB = *(const float4*)&Fl[i * 64 + nn + 4]; // broadcast
                const float fs[8] = {fA.x, fA.y, fA.z, fA.w, fB.x, fB.y, fB.z, fB.w};
                #pragma unroll
                for (int j = 0; j < 8; ++j) {
                    acc[j].x = fmaf(wv.x, fs[j], acc[j].x);
                    acc[j].y = fmaf(wv.y, fs[j], acc[j].y);
                    acc[j].z = fmaf(wv.z, fs[j], acc[j].z);
                    acc[j].w = fmaf(wv.w, fs[j], acc[j].w);
                }
            }

            #pragma unroll
            for (int j = 0; j < 8; ++j) {
                const int n = n0 + nn + j;
                const float px = posb[0 * N_ + n];
                const float py = posb[1 * N_ + n];
                const float pz = posb[2 * N_ + n];
                float4 a = acc[j];
                a.w = fmaf(-px, a.x, fmaf(-py, a.y, fmaf(-pz, a.z, a.w)));  // h
                #pragma unroll
                for (int k = 0; k < K_; ++k) {
                    const float4 r = recb[(size_t)n * K_ + k];    // contiguous bcast
                    const int slot = __float_as_int(r.w);
                    const float c  = fmaf(r.x, a.x, fmaf(r.y, a.y, fmaf(r.z, a.z, a.w)));
                    cb[((size_t)slot << 6) + lane] = __float2half(c);  // 128 B / wave
                }
            }
        }
    }
    grid.sync();

    // ---- phase 5: gather (2 reps of 64 targets/block) --------------------
    {
        float (*T)[65] = (float (*)[65])((char*)Wl);
        float (*V)[65] = (float (*)[65])((char*)Wl + 64 * 65 * sizeof(float));
        const int lane = tid & 63;
        const int w    = tid >> 6;          // 0..7

        for (int rep = 0; rep < 2; ++rep) {
            const int vb = blk + rep * FB;  // virtual block 0..1023
            const int b  = vb >> 8;         // / 256
            const int n0 = (vb & 255) * 64;

            const __half* cb  = contrib + ((size_t)b * EDGES_PER_B << 6);
            const h4*     cb4 = (const h4*)cb;

            __syncthreads();                // protect Wl/T/V reuse across reps

            for (int g = 0; g < 8; ++g) {
                const int jj = w * 8 + g;
                const int j  = n0 + jj;
                const int base = offsets[b * N_ + j];
                const int cnt  = counts[b * N_ + j];

                // lane l covers row-offset (l>>4), channels 4*(l&15)+c
                const h4* p4 = cb4 + ((size_t)base << 4) + (lane >> 4) * 16 + (lane & 15);
                float2 sl = make_float2(0.f, 0.f);
                float2 sh = make_float2(0.f, 0.f);
                const int full = cnt >> 2;      // groups of 4 rows
                int it = 0;
                for (; it + 2 <= full; it += 2) {
                    const h4 a0 = p4[0];
                    const h4 a1 = p4[64];
                    float2 t0 = __half22float2(a0.lo), t1 = __half22float2(a1.lo);
                    sl.x += t0.x + t1.x; sl.y += t0.y + t1.y;
                    t0 = __half22float2(a0.hi); t1 = __half22float2(a1.hi);
                    sh.x += t0.x + t1.x; sh.y += t0.y + t1.y;
                    p4 += 128;
                }
                if (it < full) {
                    const h4 a0 = p4[0];
                    float2 t0 = __half22float2(a0.lo);
                    sl.x += t0.x; sl.y += t0.y;
                    t0 = __half22float2(a0.hi);
                    sh.x += t0.x; sh.y += t0.y;
                }
                sl.x += __shfl_xor(sl.x, 16); sl.y += __shfl_xor(sl.y, 16);
                sh.x += __shfl_xor(sh.x, 16); sh.y += __shfl_xor(sh.y, 16);
                sl.x += __shfl_xor(sl.x, 32); sl.y += __shfl_xor(sl.y, 32);
                sh.x += __shfl_xor(sh.x, 32); sh.y += __shfl_xor(sh.y, 32);

                float tail = 0.f;
                const __half* pt = cb + (((size_t)(base + (full << 2))) << 6) + lane;
                for (int e = full << 2; e < cnt; ++e) { tail += __half2float(*pt); pt += 64; }

                T[jj][lane] = tail;
                if (lane < 16) {
                    V[jj][4 * lane + 0] = sl.x;
                    V[jj][4 * lane + 1] = sl.y;
                    V[jj][4 * lane + 2] = sh.x;
                    V[jj][4 * lane + 3] = sh.y;
                }
            }
            __syncthreads();

            float* outb = out + (size_t)b * COUT_ * N_;
            for (int r = 0; r < 8; ++r) {
                const int o = r * 8 + w;
                outb[(size_t)o * N_ + n0 + lane] = T[lane][o] + V[lane][o] + bias[o];
            }
        }
    }
}

// ===========================================================================
// FALLBACK PATH A (6 dispatches, round-5 verified): used if cooperative
// launch is rejected by the runtime.
// ===========================================================================

__global__ __launch_bounds__(256) void fc_hist(
    const int* __restrict__ nbh,
    int*       __restrict__ counts)
{
    const int gid = blockIdx.x * 256 + threadIdx.x;
    const int b   = gid / EDGES_PER_B;
    const int j   = nbh[gid];
    atomicAdd(&counts[b * N_ + j], 1);
}

__global__ __launch_bounds__(256) void fc_scan(
    const int* __restrict__ counts,
    int*       __restrict__ offsets,
    int*       __restrict__ cursor)
{
    __shared__ int s[256];
    const int b = blockIdx.x;
    const int t = threadIdx.x;
    const int base = b * N_ + t * 64;

    int sum = 0;
    #pragma unroll
    for (int e = 0; e < 64; ++e) sum += counts[base + e];
    s[t] = sum;
    __syncthreads();

    for (int d = 1; d < 256; d <<= 1) {
        const int v = (t >= d) ? s[t - d] : 0;
        __syncthreads();
        s[t] += v;
        __syncthreads();
    }

    int off = s[t] - sum;
    #pragma unroll
    for (int e = 0; e < 64; ++e) {
        const int c = counts[base + e];
        offsets[base + e] = off;
        cursor[base + e]  = off;
        off += c;
    }
}

__global__ __launch_bounds__(256) void fc_rec(
    const int*   __restrict__ nbh,
    const float* __restrict__ pos,
    int*         __restrict__ cursor,
    float4*      __restrict__ rec)
{
    const int gid = blockIdx.x * 256 + threadIdx.x;
    const int b   = gid >> 14;
    const int n   = gid & (N_ - 1);

    const int*   nbhb = nbh + (size_t)b * K_ * N_;
    const float* posb = pos + (size_t)b * 3 * N_;
    float4*      recb = rec + ((size_t)b * N_ + n) * K_;

    #pragma unroll
    for (int k = 0; k < K_; ++k) {
        const int j    = nbhb[k * N_ + n];
        const int slot = atomicAdd(&cursor[b * N_ + j], 1);
        recb[k] = make_float4(posb[j], posb[N_ + j], posb[2 * N_ + j],
                              __int_as_float(slot));
    }
}

__global__ __launch_bounds__(512, 4) void fc_contribA(
    const float*  __restrict__ feat,
    const float*  __restrict__ theta,
    const float*  __restrict__ wbias,
    const float4* __restrict__ rec,
    const float*  __restrict__ pos,
    __half*       __restrict__ contrib)
{
    __shared__ float4 Wl[CIN_ * COUT_];
    __shared__ float  Fl[CIN_ * 64];

    const int tid  = threadIdx.x;
    const int lane = tid & 63;
    const int w    = tid >> 6;

    const int blocks_per_b = N_ / 128;
    const int b     = blockIdx.x / blocks_per_b;
    const int nbase = (blockIdx.x % blocks_per_b) * 128;

    for (int e = tid; e < CIN_ * COUT_; e += 512) {
        const int i = e >> 6, o = e & 63;
        float4 wv;
        wv.x = theta[0 * CIN_ * COUT_ + i * COUT_ + o];
        wv.y = theta[1 * CIN_ * COUT_ + i * COUT_ + o];
        wv.z = theta[2 * CIN_ * COUT_ + i * COUT_ + o];
        wv.w = wbias[i * COUT_ + o];
        Wl[e] = wv;
    }

    const float*  featb = feat + (size_t)b * CIN_ * N_;
    const float*  posb  = pos  + (size_t)b * 3 * N_;
    const float4* recb  = rec  + (size_t)b * N_ * K_;
    __half*       cb    = contrib + ((size_t)b * EDGES_PER_B << 6);

    for (int t = 0; t < 2; ++t) {
        const int n0 = nbase + t * 64;

        __syncthreads();
        for (int r = 0; r < 8; ++r) {
            const int i = r * 8 + w;
            Fl[i * 64 + lane] = featb[(size_t)i * N_ + n0 + lane];
        }
        __syncthreads();

        const int nn = w * 8;
        float4 acc[8];
        #pragma unroll
        for (int j = 0; j < 8; ++j) acc[j] = make_float4(0.f, 0.f, 0.f, 0.f);

        #pragma unroll 2
        for (int i = 0; i < CIN_; ++i) {
            const float4 wv = Wl[i * 64 + lane];
            const float4 fA = *(const float4*)&Fl[i * 64 + nn];
            const float4 fB = *(const float4*)&Fl[i * 64 + nn + 4];
            const float fs[8] = {fA.x, fA.y, fA.z, fA.w, fB.x, fB.y, fB.z, fB.w};
            #pragma unroll
            for (int j = 0; j < 8; ++j) {
                acc[j].x = fmaf(wv.x, fs[j], acc[j].x);
                acc[j].y = fmaf(wv.y, fs[j], acc[j].y);
                acc[j].z = fmaf(wv.z, fs[j], acc[j].z);
                acc[j].w = fmaf(wv.w, fs[j], acc[j].w);
            }
        }

        #pragma unroll
        for (int j = 0; j < 8; ++j) {
            const int n = n0 + nn + j;
            const float px = posb[0 * N_ + n];
            const float py = posb[1 * N_ + n];
            const float pz = posb[2 * N_ + n];
            float4 a = acc[j];
            a.w = fmaf(-px, a.x, fmaf(-py, a.y, fmaf(-pz, a.z, a.w)));
            #pragma unroll
            for (int k = 0; k < K_; ++k) {
                const float4 r = recb[(size_t)n * K_ + k];
                const int slot = __float_as_int(r.w);
                const float c  = fmaf(r.x, a.x, fmaf(r.y, a.y, fmaf(r.z, a.z, a.w)));
                cb[((size_t)slot << 6) + lane] = __float2half(c);
            }
        }
    }
}

__global__ __launch_bounds__(512) void fc_gatherA(
    const __half* __restrict__ contrib,
    const int*    __restrict__ offsets,
    const int*    __restrict__ counts,
    const float*  __restrict__ bias,
    float*        __restrict__ out)
{
    __shared__ float T[64][65];
    __shared__ float V[64][65];
    const int tid  = threadIdx.x;
    const int lane = tid & 63;
    const int w    = tid >> 6;

    const int tiles_per_b = N_ / 64;
    const int b  = blockIdx.x / tiles_per_b;
    const int n0 = (blockIdx.x % tiles_per_b) * 64;

    const __half* cb  = contrib + ((size_t)b * EDGES_PER_B << 6);
    const h4*     cb4 = (const h4*)cb;

    for (int g = 0; g < 8; ++g) {
        const int jj = w * 8 + g;
        const int j  = n0 + jj;
        const int base = offsets[b * N_ + j];
        const int cnt  = counts[b * N_ + j];

        const h4* p4 = cb4 + ((size_t)base << 4) + (lane >> 4) * 16 + (lane & 15);
        float2 sl = make_float2(0.f, 0.f);
        float2 sh = make_float2(0.f, 0.f);
        const int full = cnt >> 2;
        int it = 0;
        for (; it + 2 <= full; it += 2) {
            const h4 a0 = p4[0];
            const h4 a1 = p4[64];
            float2 t0 = __half22float2(a0.lo), t1 = __half22float2(a1.lo);
            sl.x += t0.x + t1.x; sl.y += t0.y + t1.y;
            t0 = __half22float2(a0.hi); t1 = __half22float2(a1.hi);
            sh.x += t0.x + t1.x; sh.y += t0.y + t1.y;
            p4 += 128;
        }
        if (it < full) {
            const h4 a0 = p4[0];
            float2 t0 = __half22float2(a0.lo);
            sl.x += t0.x; sl.y += t0.y;
            t0 = __half22float2(a0.hi);
            sh.x += t0.x; sh.y += t0.y;
        }
        sl.x += __shfl_xor(sl.x, 16); sl.y += __shfl_xor(sl.y, 16);
        sh.x += __shfl_xor(sh.x, 16); sh.y += __shfl_xor(sh.y, 16);
        sl.x += __shfl_xor(sl.x, 32); sl.y += __shfl_xor(sl.y, 32);
        sh.x += __shfl_xor(sh.x, 32); sh.y += __shfl_xor(sh.y, 32);

        float tail = 0.f;
        const __half* pt = cb + (((size_t)(base + (full << 2))) << 6) + lane;
        for (int e = full << 2; e < cnt; ++e) { tail += __half2float(*pt); pt += 64; }

        T[jj][lane] = tail;
        if (lane < 16) {
            V[jj][4 * lane + 0] = sl.x;
            V[jj][4 * lane + 1] = sl.y;
            V[jj][4 * lane + 2] = sh.x;
            V[jj][4 * lane + 3] = sh.y;
        }
    }
    __syncthreads();

    float* outb = out + (size_t)b * COUT_ * N_;
    for (int r = 0; r < 8; ++r) {
        const int o = r * 8 + w;
        outb[(size_t)o * N_ + n0 + lane] = T[lane][o] + V[lane][o] + bias[o];
    }
}

// ===========================================================================
// PATH C (16 MiB ws): verified atomic-scatter fallback.
// ===========================================================================
__global__ __launch_bounds__(256) void flexconv_main(
    const float* __restrict__ feat,
    const float* __restrict__ theta,
    const float* __restrict__ wbias,
    const int*   __restrict__ nbh,
    const float* __restrict__ pos,
    float*       __restrict__ ws)
{
    __shared__ float4 Wl[CIN_ * COUT_];
    __shared__ float  Fl[CIN_ * 64];

    const int tid  = threadIdx.x;
    const int lane = tid & 63;
    const int w    = tid >> 6;

    const int blocks_per_b = N_ / 128;
    const int b     = blockIdx.x / blocks_per_b;
    const int nbase = (blockIdx.x % blocks_per_b) * 128;

    for (int e = tid; e < CIN_ * COUT_; e += 256) {
        const int i = e >> 6, o = e & 63;
        float4 wv;
        wv.x = theta[0 * CIN_ * COUT_ + i * COUT_ + o];
        wv.y = theta[1 * CIN_ * COUT_ + i * COUT_ + o];
        wv.z = theta[2 * CIN_ * COUT_ + i * COUT_ + o];
        wv.w = wbias[i * COUT_ + o];
        Wl[e] = wv;
    }

    const float* featb = feat + (size_t)b * CIN_ * N_;
    const float* posb  = pos  + (size_t)b * 3 * N_;
    const int*   nbhb  = nbh  + (size_t)b * K_ * N_;
    float*       wsb   = ws   + (size_t)b * N_ * COUT_;

    for (int t = 0; t < 2; ++t) {
        const int n0 = nbase + t * 64;

        __syncthreads();
        for (int r = 0; r < 16; ++r) {
            const int i = r * 4 + w;
            Fl[i * 64 + lane] = featb[(size_t)i * N_ + n0 + lane];
        }
        __syncthreads();

        for (int g = 0; g < 4; ++g) {
            const int nn = w * 16 + g * 4;
            float4 acc[4];
            #pragma unroll
            for (int j = 0; j < 4; ++j) acc[j] = make_float4(0.f, 0.f, 0.f, 0.f);

            #pragma unroll 8
            for (int i = 0; i < CIN_; ++i) {
                const float4 wv = Wl[i * 64 + lane];
                const float f0 = Fl[i * 64 + nn + 0];
                const float f1 = Fl[i * 64 + nn + 1];
                const float f2 = Fl[i * 64 + nn + 2];
                const float f3 = Fl[i * 64 + nn + 3];
                acc[0].x = fmaf(wv.x, f0, acc[0].x);
                acc[0].y = fmaf(wv.y, f0, acc[0].y);
                acc[0].z = fmaf(wv.z, f0, acc[0].z);
                acc[0].w = fmaf(wv.w, f0, acc[0].w);
                acc[1].x = fmaf(wv.x, f1, acc[1].x);
                acc[1].y = fmaf(wv.y, f1, acc[1].y);
                acc[1].z = fmaf(wv.z, f1, acc[1].z);
                acc[1].w = fmaf(wv.w, f1, acc[1].w);
                acc[2].x = fmaf(wv.x, f2, acc[2].x);
                acc[2].y = fmaf(wv.y, f2, acc[2].y);
                acc[2].z = fmaf(wv.z, f2, acc[2].z);
                acc[2].w = fmaf(wv.w, f2, acc[2].w);
                acc[3].x = fmaf(wv.x, f3, acc[3].x);
                acc[3].y = fmaf(wv.y, f3, acc[3].y);
                acc[3].z = fmaf(wv.z, f3, acc[3].z);
                acc[3].w = fmaf(wv.w, f3, acc[3].w);
            }

            #pragma unroll
            for (int j = 0; j < 4; ++j) {
                const int n = n0 + nn + j;
                const float px = posb[0 * N_ + n];
                const float py = posb[1 * N_ + n];
                const float pz = posb[2 * N_ + n];
                const float4 a = acc[j];
                #pragma unroll
                for (int k = 0; k < K_; ++k) {
                    const int idx = nbhb[k * N_ + n];
                    const float dx = posb[0 * N_ + idx] - px;
                    const float dy = posb[1 * N_ + idx] - py;
                    const float dz = posb[2 * N_ + idx] - pz;
                    const float c  = fmaf(dx, a.x, fmaf(dy, a.y, fmaf(dz, a.z, a.w)));
                    atomicAdd(&wsb[(size_t)idx * COUT_ + lane], c);
                }
            }
        }
    }
}

__global__ __launch_bounds__(256) void flexconv_finish(
    const float* __restrict__ ws,
    const float* __restrict__ bias,
    float*       __restrict__ out)
{
    __shared__ float T[64][65];
    const int tid  = threadIdx.x;
    const int lane = tid & 63;
    const int w    = tid >> 6;

    const int tiles_per_b = N_ / 64;
    const int b  = blockIdx.x / tiles_per_b;
    const int n0 = (blockIdx.x % tiles_per_b) * 64;

    const float* wsb = ws + (size_t)b * N_ * COUT_;
    for (int r = 0; r < 16; ++r) {
        const int nn = r * 4 + w;
        T[nn][lane] = wsb[(size_t)(n0 + nn) * COUT_ + lane];
    }
    __syncthreads();

    float* outb = out + (size_t)b * COUT_ * N_;
    for (int r = 0; r < 16; ++r) {
        const int o = r * 4 + w;
        outb[(size_t)o * N_ + n0 + lane] = T[lane][o] + bias[o];
    }
}

// ===========================================================================
extern "C" void kernel_launch(void* const* d_in, const int* in_sizes, int n_in,
                              void* d_out, int out_size, void* d_ws, size_t ws_size,
                              hipStream_t stream) {
    const float* features = (const float*)d_in[0];
    const float* theta    = (const float*)d_in[1];
    const float* wbias    = (const float*)d_in[2];
    const int*   nbh      = (const int*)  d_in[3];
    const float* pos      = (const float*)d_in[4];
    const float* bias     = (const float*)d_in[5];
    float* out = (float*)d_out;

    const size_t counts_bytes   = (size_t)B_ * N_ * sizeof(int);              // 256 KiB
    const size_t rec_bytes      = (size_t)TOT_EDGES * sizeof(float4);         // 8 MiB
    const size_t contribh_bytes = (size_t)TOT_EDGES * COUT_ * sizeof(__half); // 64 MiB

    // ---- fp16 counting-sort pipeline (~73 MiB) ----
    {
        size_t off = 0;
        __half* contrib = (__half*)((char*)d_ws + off); off += contribh_bytes;
        int*    offsets = (int*)   ((char*)d_ws + off); off += counts_bytes;
        int*    counts  = (int*)   ((char*)d_ws + off); off += counts_bytes;
        int*    cursor  = (int*)   ((char*)d_ws + off); off += counts_bytes;
        float4* rec     = (float4*)((char*)d_ws + off); off += rec_bytes;

        if (ws_size >= off) {
            // Try the single fused cooperative kernel first.
            void* args[] = {
                (void*)&features, (void*)&theta, (void*)&wbias, (void*)&nbh,
                (void*)&pos, (void*)&bias, (void*)&out,
                (void*)&contrib, (void*)&offsets, (void*)&counts,
                (void*)&cursor, (void*)&rec
            };
            hipError_t err = hipLaunchCooperativeKernel(
                (const void*)fc_fused, dim3(FB), dim3(FT), args, 0, stream);
            if (err == hipSuccess) return;

            // Cooperative rejected -> verified 6-dispatch path (round 5).
            hipMemsetAsync(counts, 0, counts_bytes, stream);
            fc_hist<<<TOT_EDGES / 256, 256, 0, stream>>>(nbh, counts);
            fc_scan<<<B_, 256, 0, stream>>>(counts, offsets, cursor);
            fc_rec<<<(B_ * N_) / 256, 256, 0, stream>>>(nbh, pos, cursor, rec);
            fc_contribA<<<B_ * (N_ / 128), 512, 0, stream>>>(features, theta, wbias,
                                                             rec, pos, contrib);
            fc_gatherA<<<B_ * (N_ / 64), 512, 0, stream>>>(contrib, offsets, counts,
                                                           bias, out);
            return;
        }
    }

    // ---- Path C: atomic fallback (16 MiB) ----
    {
        float* ws = (float*)d_ws;
        const size_t ws_bytes = (size_t)B_ * N_ * COUT_ * sizeof(float);
        hipMemsetAsync(ws, 0, ws_bytes, stream);
        flexconv_main<<<B_ * (N_ / 128), 256, 0, stream>>>(features, theta, wbias,
                                                           nbh, pos, ws);
        flexconv_finish<<<B_ * (N_ / 64), 256, 0, stream>>>(ws, bias, out);
    }
}

// Round 7
// 171.803 us; speedup vs baseline: 2.7200x; 2.7200x over previous
//
#include <hip/hip_runtime.h>
#include <hip/hip_fp16.h>

#define B_    4
#define CIN_  64
#define COUT_ 64
#define N_    16384
#define K_    8
#define CAP_  12     // fixed bucket capacity per target (Poisson(8): ~6% overflow)

#define EDGES_PER_B (K_ * N_)            // 131072
#define TOT_EDGES   (B_ * EDGES_PER_B)   // 524288

struct h4 { __half2 lo, hi; };   // 8 B

// ===========================================================================
// PATH NEW (~112.3 MiB ws, 3 dispatch nodes):
//   memset(cursor+ws2) -> fc_contribC -> fc_gatherC
// Fixed-capacity counting buckets replace hist/scan/rec entirely.
// ===========================================================================

// --- contrib: GEMM for ft/h per point; per-edge slot claimed inline --------
__global__ __launch_bounds__(512, 4) void fc_contribC(
    const float* __restrict__ feat,     // [B, CIN, N]
    const float* __restrict__ theta,    // [3, CIN, COUT]
    const float* __restrict__ wbias,    // [CIN, COUT]
    const int*   __restrict__ nbh,      // [B, K, N]
    const float* __restrict__ pos,      // [B, 3, N]
    int*         __restrict__ cursor,   // [B, N]  (zeroed)
    __half*      __restrict__ contrib,  // [B, N, CAP, COUT] fp16 buckets
    float*       __restrict__ ws2)      // [B, N, COUT] fp32 overflow (zeroed)
{
    __shared__ float4 Wl[CIN_ * COUT_];   // 64 KiB
    __shared__ float  Fl[CIN_ * 64];      // 16 KiB

    const int tid  = threadIdx.x;
    const int lane = tid & 63;            // o
    const int w    = tid >> 6;            // wave 0..7

    const int blocks_per_b = N_ / 128;    // 128
    const int b     = blockIdx.x / blocks_per_b;
    const int nbase = (blockIdx.x % blocks_per_b) * 128;

    for (int e = tid; e < CIN_ * COUT_; e += 512) {
        const int i = e >> 6, o = e & 63;
        float4 wv;
        wv.x = theta[0 * CIN_ * COUT_ + i * COUT_ + o];
        wv.y = theta[1 * CIN_ * COUT_ + i * COUT_ + o];
        wv.z = theta[2 * CIN_ * COUT_ + i * COUT_ + o];
        wv.w = wbias[i * COUT_ + o];
        Wl[e] = wv;
    }

    const float* featb = feat + (size_t)b * CIN_ * N_;
    const float* posb  = pos  + (size_t)b * 3 * N_;
    const int*   nbhb  = nbh  + (size_t)b * K_ * N_;
    int*         curb  = cursor + b * N_;
    __half*      cb16  = contrib + (size_t)b * N_ * CAP_ * 64;
    float*       ws2b  = ws2 + ((size_t)b * N_ << 6);

    for (int t = 0; t < 2; ++t) {
        const int n0 = nbase + t * 64;
        const int nn = w * 8;             // this wave's 8 points

        __syncthreads();   // Wl ready (t=0) / previous Fl readers done
        for (int r = 0; r < 8; ++r) {
            const int i = r * 8 + w;
            Fl[i * 64 + lane] = featb[(size_t)i * N_ + n0 + lane];
        }

        // --- edge prep: lane l claims slot for (point l>>3, edge l&7) ------
        // Issued before the GEMM; atomic/gather latency hides under the FMAs.
        const int pe = lane >> 3;                 // local point 0..7
        const int ke = lane & 7;                  // edge 0..7
        const int ne = n0 + nn + pe;
        const int je = nbhb[ke * N_ + ne];        // target of this lane's edge
        const int sle = atomicAdd(&curb[je], 1);  // slot in j's bucket
        const float qxe = posb[je];
        const float qye = posb[N_ + je];
        const float qze = posb[2 * N_ + je];

        __syncthreads();   // Fl ready

        float4 acc[8];
        #pragma unroll
        for (int j = 0; j < 8; ++j) acc[j] = make_float4(0.f, 0.f, 0.f, 0.f);

        #pragma unroll 2
        for (int i = 0; i < CIN_; ++i) {
            const float4 wv = Wl[i * 64 + lane];              // b128, conflict-free
            const float4 fA = *(const float4*)&Fl[i * 64 + nn];     // broadcast
            const float4 fB = *(const float4*)&Fl[i * 64 + nn + 4]; // broadcast
            const float fs[8] = {fA.x, fA.y, fA.z, fA.w, fB.x, fB.y, fB.z, fB.w};
            #pragma unroll
            for (int j = 0; j < 8; ++j) {
                acc[j].x = fmaf(wv.x, fs[j], acc[j].x);
                acc[j].y = fmaf(wv.y, fs[j], acc[j].y);
                acc[j].z = fmaf(wv.z, fs[j], acc[j].z);
                acc[j].w = fmaf(wv.w, fs[j], acc[j].w);
            }
        }

        #pragma unroll
        for (int p = 0; p < 8; ++p) {
            const int n = n0 + nn + p;
            const float px = posb[0 * N_ + n];
            const float py = posb[1 * N_ + n];
            const float pz = posb[2 * N_ + n];
            float4 a = acc[p];
            a.w = fmaf(-px, a.x, fmaf(-py, a.y, fmaf(-pz, a.z, a.w)));  // h
            #pragma unroll
            for (int k = 0; k < K_; ++k) {
                const int src = p * 8 + k;          // lane holding this edge's rec
                const int   jt = __shfl(je,  src);
                const int   sl = __shfl(sle, src);
                const float qx = __shfl(qxe, src);
                const float qy = __shfl(qye, src);
                const float qz = __shfl(qze, src);
                const float c  = fmaf(qx, a.x, fmaf(qy, a.y, fmaf(qz, a.z, a.w)));
                if (sl < CAP_) {
                    cb16[((size_t)jt * CAP_ + sl) * 64 + lane] = __float2half(c);
                } else {
                    atomicAdd(&ws2b[((size_t)jt << 6) + lane], c);  // rare
                }
            }
        }
    }
}

// --- gather: per target j, sum its <=CAP bucket rows + overflow + bias -----
__global__ __launch_bounds__(512) void fc_gatherC(
    const __half* __restrict__ contrib, // [B, N, CAP, COUT]
    const int*    __restrict__ cursor,  // [B, N] = total in-degree
    const float*  __restrict__ ws2,     // [B, N, COUT] overflow sums
    const float*  __restrict__ bias,
    float*        __restrict__ out)     // [B, COUT, N]
{
    __shared__ float T[64][65];
    __shared__ float V[64][65];
    const int tid  = threadIdx.x;
    const int lane = tid & 63;
    const int w    = tid >> 6;            // 0..7

    const int tiles_per_b = N_ / 64;      // 256
    const int b  = blockIdx.x / tiles_per_b;
    const int n0 = (blockIdx.x % tiles_per_b) * 64;

    const __half* cb16 = contrib + (size_t)b * N_ * CAP_ * 64;
    const float*  ws2b = ws2 + ((size_t)b * N_ << 6);

    for (int g = 0; g < 8; ++g) {
        const int jj = w * 8 + g;
        const int j  = n0 + jj;
        const int cnt_tot = cursor[b * N_ + j];
        const int cnt = cnt_tot < CAP_ ? cnt_tot : CAP_;

        const __half* row0 = cb16 + (size_t)j * CAP_ * 64;
        const h4*     p4b  = (const h4*)row0;

        // vector part: lane l covers row (l>>4) of each 4-row group, h4 col l&15
        const h4* p4 = p4b + (lane >> 4) * 16 + (lane & 15);
        float2 sl = make_float2(0.f, 0.f);
        float2 sh = make_float2(0.f, 0.f);
        const int full = cnt >> 2;          // 4-row groups (0..3)
        int it = 0;
        for (; it + 2 <= full; it += 2) {
            const h4 a0 = p4[0];
            const h4 a1 = p4[64];
            float2 t0 = __half22float2(a0.lo), t1 = __half22float2(a1.lo);
            sl.x += t0.x + t1.x; sl.y += t0.y + t1.y;
            t0 = __half22float2(a0.hi); t1 = __half22float2(a1.hi);
            sh.x += t0.x + t1.x; sh.y += t0.y + t1.y;
            p4 += 128;
        }
        if (it < full) {
            const h4 a0 = p4[0];
            float2 t0 = __half22float2(a0.lo);
            sl.x += t0.x; sl.y += t0.y;
            t0 = __half22float2(a0.hi);
            sh.x += t0.x; sh.y += t0.y;
        }
        sl.x += __shfl_xor(sl.x, 16); sl.y += __shfl_xor(sl.y, 16);
        sh.x += __shfl_xor(sh.x, 16); sh.y += __shfl_xor(sh.y, 16);
        sl.x += __shfl_xor(sl.x, 32); sl.y += __shfl_xor(sl.y, 32);
        sh.x += __shfl_xor(sh.x, 32); sh.y += __shfl_xor(sh.y, 32);

        // scalar tail rows + overflow accumulator (coalesced 256 B)
        float tail = ws2b[((size_t)j << 6) + lane];
        const __half* pt = row0 + ((size_t)(full << 2)) * 64 + lane;
        for (int e = full << 2; e < cnt; ++e) { tail += __half2float(*pt); pt += 64; }

        T[jj][lane] = tail;
        if (lane < 16) {
            V[jj][4 * lane + 0] = sl.x;
            V[jj][4 * lane + 1] = sl.y;
            V[jj][4 * lane + 2] = sh.x;
            V[jj][4 * lane + 3] = sh.y;
        }
    }
    __syncthreads();

    float* outb = out + (size_t)b * COUT_ * N_;
    for (int r = 0; r < 8; ++r) {
        const int o = r * 8 + w;
        outb[(size_t)o * N_ + n0 + lane] = T[lane][o] + V[lane][o] + bias[o];
    }
}

// ===========================================================================
// FALLBACK A (round-5 verified, 6 dispatches, ~72.75 MiB ws)
// ===========================================================================

__global__ __launch_bounds__(256) void fc_hist(
    const int* __restrict__ nbh,
    int*       __restrict__ counts)
{
    const int gid = blockIdx.x * 256 + threadIdx.x;
    const int b   = gid / EDGES_PER_B;
    const int j   = nbh[gid];
    atomicAdd(&counts[b * N_ + j], 1);
}

__global__ __launch_bounds__(256) void fc_scan(
    const int* __restrict__ counts,
    int*       __restrict__ offsets,
    int*       __restrict__ cursor)
{
    __shared__ int s[256];
    const int b = blockIdx.x;
    const int t = threadIdx.x;
    const int base = b * N_ + t * 64;

    int sum = 0;
    #pragma unroll
    for (int e = 0; e < 64; ++e) sum += counts[base + e];
    s[t] = sum;
    __syncthreads();

    for (int d = 1; d < 256; d <<= 1) {
        const int v = (t >= d) ? s[t - d] : 0;
        __syncthreads();
        s[t] += v;
        __syncthreads();
    }

    int off = s[t] - sum;
    #pragma unroll
    for (int e = 0; e < 64; ++e) {
        const int c = counts[base + e];
        offsets[base + e] = off;
        cursor[base + e]  = off;
        off += c;
    }
}

__global__ __launch_bounds__(256) void fc_rec(
    const int*   __restrict__ nbh,
    const float* __restrict__ pos,
    int*         __restrict__ cursor,
    float4*      __restrict__ rec)
{
    const int gid = blockIdx.x * 256 + threadIdx.x;
    const int b   = gid >> 14;
    const int n   = gid & (N_ - 1);

    const int*   nbhb = nbh + (size_t)b * K_ * N_;
    const float* posb = pos + (size_t)b * 3 * N_;
    float4*      recb = rec + ((size_t)b * N_ + n) * K_;

    #pragma unroll
    for (int k = 0; k < K_; ++k) {
        const int j    = nbhb[k * N_ + n];
        const int slot = atomicAdd(&cursor[b * N_ + j], 1);
        recb[k] = make_float4(posb[j], posb[N_ + j], posb[2 * N_ + j],
                              __int_as_float(slot));
    }
}

__global__ __launch_bounds__(512, 4) void fc_contribA(
    const float*  __restrict__ feat,
    const float*  __restrict__ theta,
    const float*  __restrict__ wbias,
    const float4* __restrict__ rec,
    const float*  __restrict__ pos,
    __half*       __restrict__ contrib)
{
    __shared__ float4 Wl[CIN_ * COUT_];
    __shared__ float  Fl[CIN_ * 64];

    const int tid  = threadIdx.x;
    const int lane = tid & 63;
    const int w    = tid >> 6;

    const int blocks_per_b = N_ / 128;
    const int b     = blockIdx.x / blocks_per_b;
    const int nbase = (blockIdx.x % blocks_per_b) * 128;

    for (int e = tid; e < CIN_ * COUT_; e += 512) {
        const int i = e >> 6, o = e & 63;
        float4 wv;
        wv.x = theta[0 * CIN_ * COUT_ + i * COUT_ + o];
        wv.y = theta[1 * CIN_ * COUT_ + i * COUT_ + o];
        wv.z = theta[2 * CIN_ * COUT_ + i * COUT_ + o];
        wv.w = wbias[i * COUT_ + o];
        Wl[e] = wv;
    }

    const float*  featb = feat + (size_t)b * CIN_ * N_;
    const float*  posb  = pos  + (size_t)b * 3 * N_;
    const float4* recb  = rec  + (size_t)b * N_ * K_;
    __half*       cb    = contrib + ((size_t)b * EDGES_PER_B << 6);

    for (int t = 0; t < 2; ++t) {
        const int n0 = nbase + t * 64;

        __syncthreads();
        for (int r = 0; r < 8; ++r) {
            const int i = r * 8 + w;
            Fl[i * 64 + lane] = featb[(size_t)i * N_ + n0 + lane];
        }
        __syncthreads();

        const int nn = w * 8;
        float4 acc[8];
        #pragma unroll
        for (int j = 0; j < 8; ++j) acc[j] = make_float4(0.f, 0.f, 0.f, 0.f);

        #pragma unroll 2
        for (int i = 0; i < CIN_; ++i) {
            const float4 wv = Wl[i * 64 + lane];
            const float4 fA = *(const float4*)&Fl[i * 64 + nn];
            const float4 fB = *(const float4*)&Fl[i * 64 + nn + 4];
            const float fs[8] = {fA.x, fA.y, fA.z, fA.w, fB.x, fB.y, fB.z, fB.w};
            #pragma unroll
            for (int j = 0; j < 8; ++j) {
                acc[j].x = fmaf(wv.x, fs[j], acc[j].x);
                acc[j].y = fmaf(wv.y, fs[j], acc[j].y);
                acc[j].z = fmaf(wv.z, fs[j], acc[j].z);
                acc[j].w = fmaf(wv.w, fs[j], acc[j].w);
            }
        }

        #pragma unroll
        for (int j = 0; j < 8; ++j) {
            const int n = n0 + nn + j;
            const float px = posb[0 * N_ + n];
            const float py = posb[1 * N_ + n];
            const float pz = posb[2 * N_ + n];
            float4 a = acc[j];
            a.w = fmaf(-px, a.x, fmaf(-py, a.y, fmaf(-pz, a.z, a.w)));
            #pragma unroll
            for (int k = 0; k < K_; ++k) {
                const float4 r = recb[(size_t)n * K_ + k];
                const int slot = __float_as_int(r.w);
                const float c  = fmaf(r.x, a.x, fmaf(r.y, a.y, fmaf(r.z, a.z, a.w)));
                cb[((size_t)slot << 6) + lane] = __float2half(c);
            }
        }
    }
}

__global__ __launch_bounds__(512) void fc_gatherA(
    const __half* __restrict__ contrib,
    const int*    __restrict__ offsets,
    const int*    __restrict__ counts,
    const float*  __restrict__ bias,
    float*        __restrict__ out)
{
    __shared__ float T[64][65];
    __shared__ float V[64][65];
    const int tid  = threadIdx.x;
    const int lane = tid & 63;
    const int w    = tid >> 6;

    const int tiles_per_b = N_ / 64;
    const int b  = blockIdx.x / tiles_per_b;
    const int n0 = (blockIdx.x % tiles_per_b) * 64;

    const __half* cb  = contrib + ((size_t)b * EDGES_PER_B << 6);
    const h4*     cb4 = (const h4*)cb;

    for (int g = 0; g < 8; ++g) {
        const int jj = w * 8 + g;
        const int j  = n0 + jj;
        const int base = offsets[b * N_ + j];
        const int cnt  = counts[b * N_ + j];

        const h4* p4 = cb4 + ((size_t)base << 4) + (lane >> 4) * 16 + (lane & 15);
        float2 sl = make_float2(0.f, 0.f);
        float2 sh = make_float2(0.f, 0.f);
        const int full = cnt >> 2;
        int it = 0;
        for (; it + 2 <= full; it += 2) {
            const h4 a0 = p4[0];
            const h4 a1 = p4[64];
            float2 t0 = __half22float2(a0.lo), t1 = __half22float2(a1.lo);
            sl.x += t0.x + t1.x; sl.y += t0.y + t1.y;
            t0 = __half22float2(a0.hi); t1 = __half22float2(a1.hi);
            sh.x += t0.x + t1.x; sh.y += t0.y + t1.y;
            p4 += 128;
        }
        if (it < full) {
            const h4 a0 = p4[0];
            float2 t0 = __half22float2(a0.lo);
            sl.x += t0.x; sl.y += t0.y;
            t0 = __half22float2(a0.hi);
            sh.x += t0.x; sh.y += t0.y;
        }
        sl.x += __shfl_xor(sl.x, 16); sl.y += __shfl_xor(sl.y, 16);
        sh.x += __shfl_xor(sh.x, 16); sh.y += __shfl_xor(sh.y, 16);
        sl.x += __shfl_xor(sl.x, 32); sl.y += __shfl_xor(sl.y, 32);
        sh.x += __shfl_xor(sh.x, 32); sh.y += __shfl_xor(sh.y, 32);

        float tail = 0.f;
        const __half* pt = cb + (((size_t)(base + (full << 2))) << 6) + lane;
        for (int e = full << 2; e < cnt; ++e) { tail += __half2float(*pt); pt += 64; }

        T[jj][lane] = tail;
        if (lane < 16) {
            V[jj][4 * lane + 0] = sl.x;
            V[jj][4 * lane + 1] = sl.y;
            V[jj][4 * lane + 2] = sh.x;
            V[jj][4 * lane + 3] = sh.y;
        }
    }
    __syncthreads();

    float* outb = out + (size_t)b * COUT_ * N_;
    for (int r = 0; r < 8; ++r) {
        const int o = r * 8 + w;
        outb[(size_t)o * N_ + n0 + lane] = T[lane][o] + V[lane][o] + bias[o];
    }
}

// ===========================================================================
// PATH C (16 MiB ws): verified atomic-scatter fallback.
// ===========================================================================
__global__ __launch_bounds__(256) void flexconv_main(
    const float* __restrict__ feat,
    const float* __restrict__ theta,
    const float* __restrict__ wbias,
    const int*   __restrict__ nbh,
    const float* __restrict__ pos,
    float*       __restrict__ ws)
{
    __shared__ float4 Wl[CIN_ * COUT_];
    __shared__ float  Fl[CIN_ * 64];

    const int tid  = threadIdx.x;
    const int lane = tid & 63;
    const int w    = tid >> 6;

    const int blocks_per_b = N_ / 128;
    const int b     = blockIdx.x / blocks_per_b;
    const int nbase = (blockIdx.x % blocks_per_b) * 128;

    for (int e = tid; e < CIN_ * COUT_; e += 256) {
        const int i = e >> 6, o = e & 63;
        float4 wv;
        wv.x = theta[0 * CIN_ * COUT_ + i * COUT_ + o];
        wv.y = theta[1 * CIN_ * COUT_ + i * COUT_ + o];
        wv.z = theta[2 * CIN_ * COUT_ + i * COUT_ + o];
        wv.w = wbias[i * COUT_ + o];
        Wl[e] = wv;
    }

    const float* featb = feat + (size_t)b * CIN_ * N_;
    const float* posb  = pos  + (size_t)b * 3 * N_;
    const int*   nbhb  = nbh  + (size_t)b * K_ * N_;
    float*       wsb   = ws   + (size_t)b * N_ * COUT_;

    for (int t = 0; t < 2; ++t) {
        const int n0 = nbase + t * 64;

        __syncthreads();
        for (int r = 0; r < 16; ++r) {
            const int i = r * 4 + w;
            Fl[i * 64 + lane] = featb[(size_t)i * N_ + n0 + lane];
        }
        __syncthreads();

        for (int g = 0; g < 4; ++g) {
            const int nn = w * 16 + g * 4;
            float4 acc[4];
            #pragma unroll
            for (int j = 0; j < 4; ++j) acc[j] = make_float4(0.f, 0.f, 0.f, 0.f);

            #pragma unroll 8
            for (int i = 0; i < CIN_; ++i) {
                const float4 wv = Wl[i * 64 + lane];
                const float f0 = Fl[i * 64 + nn + 0];
                const float f1 = Fl[i * 64 + nn + 1];
                const float f2 = Fl[i * 64 + nn + 2];
                const float f3 = Fl[i * 64 + nn + 3];
                acc[0].x = fmaf(wv.x, f0, acc[0].x);
                acc[0].y = fmaf(wv.y, f0, acc[0].y);
                acc[0].z = fmaf(wv.z, f0, acc[0].z);
                acc[0].w = fmaf(wv.w, f0, acc[0].w);
                acc[1].x = fmaf(wv.x, f1, acc[1].x);
                acc[1].y = fmaf(wv.y, f1, acc[1].y);
                acc[1].z = fmaf(wv.z, f1, acc[1].z);
                acc[1].w = fmaf(wv.w, f1, acc[1].w);
                acc[2].x = fmaf(wv.x, f2, acc[2].x);
                acc[2].y = fmaf(wv.y, f2, acc[2].y);
                acc[2].z = fmaf(wv.z, f2, acc[2].z);
                acc[2].w = fmaf(wv.w, f2, acc[2].w);
                acc[3].x = fmaf(wv.x, f3, acc[3].x);
                acc[3].y = fmaf(wv.y, f3, acc[3].y);
                acc[3].z = fmaf(wv.z, f3, acc[3].z);
                acc[3].w = fmaf(wv.w, f3, acc[3].w);
            }

            #pragma unroll
            for (int j = 0; j < 4; ++j) {
                const int n = n0 + nn + j;
                const float px = posb[0 * N_ + n];
                const float py = posb[1 * N_ + n];
                const float pz = posb[2 * N_ + n];
                const float4 a = acc[j];
                #pragma unroll
                for (int k = 0; k < K_; ++k) {
                    const int idx = nbhb[k * N_ + n];
                    const float dx = posb[0 * N_ + idx] - px;
                    const float dy = posb[1 * N_ + idx] - py;
                    const float dz = posb[2 * N_ + idx] - pz;
                    const float c  = fmaf(dx, a.x, fmaf(dy, a.y, fmaf(dz, a.z, a.w)));
                    atomicAdd(&wsb[(size_t)idx * COUT_ + lane], c);
                }
            }
        }
    }
}

__global__ __launch_bounds__(256) void flexconv_finish(
    const float* __restrict__ ws,
    const float* __restrict__ bias,
    float*       __restrict__ out)
{
    __shared__ float T[64][65];
    const int tid  = threadIdx.x;
    const int lane = tid & 63;
    const int w    = tid >> 6;

    const int tiles_per_b = N_ / 64;
    const int b  = blockIdx.x / tiles_per_b;
    const int n0 = (blockIdx.x % tiles_per_b) * 64;

    const float* wsb = ws + (size_t)b * N_ * COUT_;
    for (int r = 0; r < 16; ++r) {
        const int nn = r * 4 + w;
        T[nn][lane] = wsb[(size_t)(n0 + nn) * COUT_ + lane];
    }
    __syncthreads();

    float* outb = out + (size_t)b * COUT_ * N_;
    for (int r = 0; r < 16; ++r) {
        const int o = r * 4 + w;
        outb[(size_t)o * N_ + n0 + lane] = T[lane][o] + bias[o];
    }
}

// ===========================================================================
extern "C" void kernel_launch(void* const* d_in, const int* in_sizes, int n_in,
                              void* d_out, int out_size, void* d_ws, size_t ws_size,
                              hipStream_t stream) {
    const float* features = (const float*)d_in[0];
    const float* theta    = (const float*)d_in[1];
    const float* wbias    = (const float*)d_in[2];
    const int*   nbh      = (const int*)  d_in[3];
    const float* pos      = (const float*)d_in[4];
    const float* bias     = (const float*)d_in[5];
    float* out = (float*)d_out;

    const size_t counts_bytes   = (size_t)B_ * N_ * sizeof(int);              // 256 KiB
    const size_t rec_bytes      = (size_t)TOT_EDGES * sizeof(float4);         // 8 MiB
    const size_t contribh_bytes = (size_t)TOT_EDGES * COUT_ * sizeof(__half); // 64 MiB

    // ---- Path NEW: fixed-capacity buckets, 3 nodes (~112.3 MiB) ----
    {
        const size_t bucket_bytes = (size_t)B_ * N_ * CAP_ * 64 * sizeof(__half); // 96 MiB
        const size_t ws2_bytes    = (size_t)B_ * N_ * 64 * sizeof(float);         // 16 MiB

        size_t off = 0;
        __half* contrib = (__half*)((char*)d_ws + off); off += bucket_bytes;
        int*    cursor  = (int*)   ((char*)d_ws + off); off += counts_bytes;
        float*  ws2     = (float*) ((char*)d_ws + off); off += ws2_bytes;

        if (ws_size >= off) {
            // one memset covers cursor + ws2 (contiguous)
            hipMemsetAsync(cursor, 0, counts_bytes + ws2_bytes, stream);
            fc_contribC<<<B_ * (N_ / 128), 512, 0, stream>>>(features, theta, wbias,
                                                             nbh, pos, cursor,
                                                             contrib, ws2);
            fc_gatherC<<<B_ * (N_ / 64), 512, 0, stream>>>(contrib, cursor, ws2,
                                                           bias, out);
            return;
        }
    }

    // ---- Fallback A: round-5 verified 6-dispatch pipeline (~72.75 MiB) ----
    {
        size_t off = 0;
        __half* contrib = (__half*)((char*)d_ws + off); off += contribh_bytes;
        int*    offsets = (int*)   ((char*)d_ws + off); off += counts_bytes;
        int*    counts  = (int*)   ((char*)d_ws + off); off += counts_bytes;
        int*    cursor  = (int*)   ((char*)d_ws + off); off += counts_bytes;
        float4* rec     = (float4*)((char*)d_ws + off); off += rec_bytes;

        if (ws_size >= off) {
            hipMemsetAsync(counts, 0, counts_bytes, stream);
            fc_hist<<<TOT_EDGES / 256, 256, 0, stream>>>(nbh, counts);
            fc_scan<<<B_, 256, 0, stream>>>(counts, offsets, cursor);
            fc_rec<<<(B_ * N_) / 256, 256, 0, stream>>>(nbh, pos, cursor, rec);
            fc_contribA<<<B_ * (N_ / 128), 512, 0, stream>>>(features, theta, wbias,
                                                             rec, pos, contrib);
            fc_gatherA<<<B_ * (N_ / 64), 512, 0, stream>>>(contrib, offsets, counts,
                                                           bias, out);
            return;
        }
    }

    // ---- Path C: atomic fallback (16 MiB) ----
    {
        float* ws = (float*)d_ws;
        const size_t ws_bytes = (size_t)B_ * N_ * COUT_ * sizeof(float);
        hipMemsetAsync(ws, 0, ws_bytes, stream);
        flexconv_main<<<B_ * (N_ / 128), 256, 0, stream>>>(features, theta, wbias,
                                                           nbh, pos, ws);
        flexconv_finish<<<B_ * (N_ / 64), 256, 0, stream>>>(ws, bias, out);
    }
}

// Round 8
// 162.548 us; speedup vs baseline: 2.8749x; 1.0569x over previous
//
#include <hip/hip_runtime.h>
#include <hip/hip_fp16.h>

#define B_    4
#define CIN_  64
#define COUT_ 64
#define N_    16384
#define K_    8
#define CAP_  16     // index-bucket capacity (Poisson(8): P(>16) ~ 0.3%)

#define EDGES_PER_B (K_ * N_)            // 131072
#define TOT_EDGES   (B_ * EDGES_PER_B)   // 524288

// ===========================================================================
// PATH D (~52.3 MiB ws, 3 dispatch nodes):
//   memset(cursor+ws2) -> fc_contribD -> fc_gatherD
// Factorization: out[j][o] = pos_j . (sum ft_n[o]) + sum h_n[o]
//   => per-edge intermediate is just a SOURCE INDEX (4 B); heavy data is the
//      per-source row ftfb16[n][o] = {ft0,ft1,ft2,h} (4xfp16), written ONCE
//      densely, gathered K times from L2/L3.
// ===========================================================================

__device__ __forceinline__ unsigned pack_h2(float a, float b) {
    return (unsigned)__half_as_ushort(__float2half(a))
         | ((unsigned)__half_as_ushort(__float2half(b)) << 16);
}

__device__ __forceinline__ float edge_dot(uint2 v, float qx, float qy, float qz) {
    const float f0 = __half2float(__ushort_as_half((unsigned short)(v.x)));
    const float f1 = __half2float(__ushort_as_half((unsigned short)(v.x >> 16)));
    const float f2 = __half2float(__ushort_as_half((unsigned short)(v.y)));
    const float f3 = __half2float(__ushort_as_half((unsigned short)(v.y >> 16)));
    return fmaf(qx, f0, fmaf(qy, f1, fmaf(qz, f2, f3)));
}

// --- contrib: GEMM -> dense ftfb16 row per point; bucket index per edge ----
__global__ __launch_bounds__(512, 4) void fc_contribD(
    const float* __restrict__ feat,     // [B, CIN, N]
    const float* __restrict__ theta,    // [3, CIN, COUT]
    const float* __restrict__ wbias,    // [CIN, COUT]
    const int*   __restrict__ nbh,      // [B, K, N]
    const float* __restrict__ pos,      // [B, 3, N]
    int*         __restrict__ cursor,   // [B, N]   (zeroed)
    int*         __restrict__ bucket,   // [B, N, CAP] source indices
    uint2*       __restrict__ ftfb,     // [B, N, 64] packed 4xfp16
    float*       __restrict__ ws2)      // [B, N, 64] fp32 overflow (zeroed)
{
    __shared__ float4 Wl[CIN_ * COUT_];   // 64 KiB
    __shared__ float  Fl[CIN_ * 64];      // 16 KiB

    const int tid  = threadIdx.x;
    const int lane = tid & 63;            // o
    const int w    = tid >> 6;            // wave 0..7

    const int blocks_per_b = N_ / 128;    // 128
    const int b     = blockIdx.x / blocks_per_b;
    const int nbase = (blockIdx.x % blocks_per_b) * 128;

    for (int e = tid; e < CIN_ * COUT_; e += 512) {
        const int i = e >> 6, o = e & 63;
        float4 wv;
        wv.x = theta[0 * CIN_ * COUT_ + i * COUT_ + o];
        wv.y = theta[1 * CIN_ * COUT_ + i * COUT_ + o];
        wv.z = theta[2 * CIN_ * COUT_ + i * COUT_ + o];
        wv.w = wbias[i * COUT_ + o];
        Wl[e] = wv;
    }

    const float* featb = feat + (size_t)b * CIN_ * N_;
    const float* posb  = pos  + (size_t)b * 3 * N_;
    const int*   nbhb  = nbh  + (size_t)b * K_ * N_;
    int*         curb  = cursor + b * N_;
    int*         bkb   = bucket + (size_t)b * N_ * CAP_;
    uint2*       fbb   = ftfb + ((size_t)b * N_ << 6);
    float*       ws2b  = ws2 + ((size_t)b * N_ << 6);

    for (int t = 0; t < 2; ++t) {
        const int n0 = nbase + t * 64;
        const int nn = w * 8;             // this wave's 8 points

        __syncthreads();   // Wl ready (t=0) / previous Fl readers done
        for (int r = 0; r < 8; ++r) {
            const int i = r * 8 + w;
            Fl[i * 64 + lane] = featb[(size_t)i * N_ + n0 + lane];
        }

        // --- edge prep: lane l claims slot for (point l>>3, edge l&7) ------
        const int pe = lane >> 3;                 // local point 0..7
        const int ke = lane & 7;                  // edge 0..7
        const int ne = n0 + nn + pe;
        const int je = nbhb[ke * N_ + ne];
        const int sle = atomicAdd(&curb[je], 1);
        if (sle < CAP_) bkb[je * CAP_ + sle] = ne;   // 4-B scattered store

        __syncthreads();   // Fl ready

        float4 acc[8];
        #pragma unroll
        for (int j = 0; j < 8; ++j) acc[j] = make_float4(0.f, 0.f, 0.f, 0.f);

        #pragma unroll 2
        for (int i = 0; i < CIN_; ++i) {
            const float4 wv = Wl[i * 64 + lane];              // b128, conflict-free
            const float4 fA = *(const float4*)&Fl[i * 64 + nn];     // broadcast
            const float4 fB = *(const float4*)&Fl[i * 64 + nn + 4]; // broadcast
            const float fs[8] = {fA.x, fA.y, fA.z, fA.w, fB.x, fB.y, fB.z, fB.w};
            #pragma unroll
            for (int j = 0; j < 8; ++j) {
                acc[j].x = fmaf(wv.x, fs[j], acc[j].x);
                acc[j].y = fmaf(wv.y, fs[j], acc[j].y);
                acc[j].z = fmaf(wv.z, fs[j], acc[j].z);
                acc[j].w = fmaf(wv.w, fs[j], acc[j].w);
            }
        }

        const unsigned long long ovf = __ballot(sle >= CAP_);   // wave-uniform

        #pragma unroll
        for (int p = 0; p < 8; ++p) {
            const int n = n0 + nn + p;
            const float px = posb[0 * N_ + n];
            const float py = posb[1 * N_ + n];
            const float pz = posb[2 * N_ + n];
            float4 a = acc[p];
            a.w = fmaf(-px, a.x, fmaf(-py, a.y, fmaf(-pz, a.z, a.w)));  // h

            // dense coalesced 8-B store: the ONLY per-point heavy write
            uint2 v;
            v.x = pack_h2(a.x, a.y);
            v.y = pack_h2(a.z, a.w);
            fbb[((size_t)n << 6) + lane] = v;

            // rare overflow edges: fp32 atomic into ws2 (wave-uniform masks)
            const unsigned m8 = (unsigned)((ovf >> (p * 8)) & 0xFFull);
            if (m8) {
                #pragma unroll
                for (int k = 0; k < 8; ++k) {
                    if ((m8 >> k) & 1) {
                        const int src = p * 8 + k;
                        const int jt = __shfl(je, src);
                        const float qx = posb[jt];              // broadcast
                        const float qy = posb[N_ + jt];
                        const float qz = posb[2 * N_ + jt];
                        const float c = fmaf(qx, a.x,
                                        fmaf(qy, a.y,
                                        fmaf(qz, a.z, a.w)));
                        atomicAdd(&ws2b[((size_t)jt << 6) + lane], c);
                    }
                }
            }
        }
    }
}

// --- gather: per target j, sum ftfb rows of its bucket sources -------------
__global__ __launch_bounds__(512, 8) void fc_gatherD(
    const uint2* __restrict__ ftfb,     // [B, N, 64]
    const int*   __restrict__ bucket,   // [B, N, CAP]
    const int*   __restrict__ cursor,   // [B, N] total in-degree
    const float* __restrict__ ws2,      // [B, N, 64] overflow sums
    const float* __restrict__ pos,      // [B, 3, N]
    const float* __restrict__ bias,
    float*       __restrict__ out)      // [B, COUT, N]
{
    __shared__ float T[64][65];          // 16.25 KiB -> 4 blocks/CU
    const int tid  = threadIdx.x;
    const int lane = tid & 63;           // o
    const int w    = tid >> 6;           // 0..7

    const int tiles_per_b = N_ / 64;     // 256
    const int b  = blockIdx.x / tiles_per_b;
    const int n0 = (blockIdx.x % tiles_per_b) * 64;

    const uint2* fbb  = ftfb + ((size_t)b * N_ << 6);
    const int*   bkb  = bucket + (size_t)b * N_ * CAP_;
    const float* posb = pos + (size_t)b * 3 * N_;
    const float* ws2b = ws2 + ((size_t)b * N_ << 6);

    for (int g = 0; g < 8; ++g) {
        const int jj = w * 8 + g;
        const int j  = n0 + jj;
        const int cnt_tot = cursor[b * N_ + j];
        const int cnt = cnt_tot < CAP_ ? cnt_tot : CAP_;
        const float qx = posb[j];
        const float qy = posb[N_ + j];
        const float qz = posb[2 * N_ + j];

        // parallel index fetch: lane e holds bucket entry e
        const int myidx = (lane < cnt) ? bkb[j * CAP_ + lane] : 0;

        float acc = (cnt_tot > CAP_) ? ws2b[((size_t)j << 6) + lane] : 0.f;

        int e = 0;
        for (; e + 4 <= cnt; e += 4) {          // 4 row loads in flight
            const int m0 = __shfl(myidx, e + 0);
            const int m1 = __shfl(myidx, e + 1);
            const int m2 = __shfl(myidx, e + 2);
            const int m3 = __shfl(myidx, e + 3);
            const uint2 v0 = fbb[((size_t)m0 << 6) + lane];
            const uint2 v1 = fbb[((size_t)m1 << 6) + lane];
            const uint2 v2 = fbb[((size_t)m2 << 6) + lane];
            const uint2 v3 = fbb[((size_t)m3 << 6) + lane];
            acc += edge_dot(v0, qx, qy, qz);
            acc += edge_dot(v1, qx, qy, qz);
            acc += edge_dot(v2, qx, qy, qz);
            acc += edge_dot(v3, qx, qy, qz);
        }
        for (; e < cnt; ++e) {
            const int m = __shfl(myidx, e);
            const uint2 v = fbb[((size_t)m << 6) + lane];
            acc += edge_dot(v, qx, qy, qz);
        }
        T[jj][lane] = acc;
    }
    __syncthreads();

    float* outb = out + (size_t)b * COUT_ * N_;
    for (int r = 0; r < 8; ++r) {
        const int o = r * 8 + w;
        outb[(size_t)o * N_ + n0 + lane] = T[lane][o] + bias[o];  // coalesced
    }
}

// ===========================================================================
// PATH C (16 MiB ws): verified atomic-scatter fallback.
// ===========================================================================
__global__ __launch_bounds__(256) void flexconv_main(
    const float* __restrict__ feat,
    const float* __restrict__ theta,
    const float* __restrict__ wbias,
    const int*   __restrict__ nbh,
    const float* __restrict__ pos,
    float*       __restrict__ ws)
{
    __shared__ float4 Wl[CIN_ * COUT_];
    __shared__ float  Fl[CIN_ * 64];

    const int tid  = threadIdx.x;
    const int lane = tid & 63;
    const int w    = tid >> 6;

    const int blocks_per_b = N_ / 128;
    const int b     = blockIdx.x / blocks_per_b;
    const int nbase = (blockIdx.x % blocks_per_b) * 128;

    for (int e = tid; e < CIN_ * COUT_; e += 256) {
        const int i = e >> 6, o = e & 63;
        float4 wv;
        wv.x = theta[0 * CIN_ * COUT_ + i * COUT_ + o];
        wv.y = theta[1 * CIN_ * COUT_ + i * COUT_ + o];
        wv.z = theta[2 * CIN_ * COUT_ + i * COUT_ + o];
        wv.w = wbias[i * COUT_ + o];
        Wl[e] = wv;
    }

    const float* featb = feat + (size_t)b * CIN_ * N_;
    const float* posb  = pos  + (size_t)b * 3 * N_;
    const int*   nbhb  = nbh  + (size_t)b * K_ * N_;
    float*       wsb   = ws   + (size_t)b * N_ * COUT_;

    for (int t = 0; t < 2; ++t) {
        const int n0 = nbase + t * 64;

        __syncthreads();
        for (int r = 0; r < 16; ++r) {
            const int i = r * 4 + w;
            Fl[i * 64 + lane] = featb[(size_t)i * N_ + n0 + lane];
        }
        __syncthreads();

        for (int g = 0; g < 4; ++g) {
            const int nn = w * 16 + g * 4;
            float4 acc[4];
            #pragma unroll
            for (int j = 0; j < 4; ++j) acc[j] = make_float4(0.f, 0.f, 0.f, 0.f);

            #pragma unroll 8
            for (int i = 0; i < CIN_; ++i) {
                const float4 wv = Wl[i * 64 + lane];
                const float f0 = Fl[i * 64 + nn + 0];
                const float f1 = Fl[i * 64 + nn + 1];
                const float f2 = Fl[i * 64 + nn + 2];
                const float f3 = Fl[i * 64 + nn + 3];
                acc[0].x = fmaf(wv.x, f0, acc[0].x);
                acc[0].y = fmaf(wv.y, f0, acc[0].y);
                acc[0].z = fmaf(wv.z, f0, acc[0].z);
                acc[0].w = fmaf(wv.w, f0, acc[0].w);
                acc[1].x = fmaf(wv.x, f1, acc[1].x);
                acc[1].y = fmaf(wv.y, f1, acc[1].y);
                acc[1].z = fmaf(wv.z, f1, acc[1].z);
                acc[1].w = fmaf(wv.w, f1, acc[1].w);
                acc[2].x = fmaf(wv.x, f2, acc[2].x);
                acc[2].y = fmaf(wv.y, f2, acc[2].y);
                acc[2].z = fmaf(wv.z, f2, acc[2].z);
                acc[2].w = fmaf(wv.w, f2, acc[2].w);
                acc[3].x = fmaf(wv.x, f3, acc[3].x);
                acc[3].y = fmaf(wv.y, f3, acc[3].y);
                acc[3].z = fmaf(wv.z, f3, acc[3].z);
                acc[3].w = fmaf(wv.w, f3, acc[3].w);
            }

            #pragma unroll
            for (int j = 0; j < 4; ++j) {
                const int n = n0 + nn + j;
                const float px = posb[0 * N_ + n];
                const float py = posb[1 * N_ + n];
                const float pz = posb[2 * N_ + n];
                const float4 a = acc[j];
                #pragma unroll
                for (int k = 0; k < K_; ++k) {
                    const int idx = nbhb[k * N_ + n];
                    const float dx = posb[0 * N_ + idx] - px;
                    const float dy = posb[1 * N_ + idx] - py;
                    const float dz = posb[2 * N_ + idx] - pz;
                    const float c  = fmaf(dx, a.x, fmaf(dy, a.y, fmaf(dz, a.z, a.w)));
                    atomicAdd(&wsb[(size_t)idx * COUT_ + lane], c);
                }
            }
        }
    }
}

__global__ __launch_bounds__(256) void flexconv_finish(
    const float* __restrict__ ws,
    const float* __restrict__ bias,
    float*       __restrict__ out)
{
    __shared__ float T[64][65];
    const int tid  = threadIdx.x;
    const int lane = tid & 63;
    const int w    = tid >> 6;

    const int tiles_per_b = N_ / 64;
    const int b  = blockIdx.x / tiles_per_b;
    const int n0 = (blockIdx.x % tiles_per_b) * 64;

    const float* wsb = ws + (size_t)b * N_ * COUT_;
    for (int r = 0; r < 16; ++r) {
        const int nn = r * 4 + w;
        T[nn][lane] = wsb[(size_t)(n0 + nn) * COUT_ + lane];
    }
    __syncthreads();

    float* outb = out + (size_t)b * COUT_ * N_;
    for (int r = 0; r < 16; ++r) {
        const int o = r * 4 + w;
        outb[(size_t)o * N_ + n0 + lane] = T[lane][o] + bias[o];
    }
}

// ===========================================================================
extern "C" void kernel_launch(void* const* d_in, const int* in_sizes, int n_in,
                              void* d_out, int out_size, void* d_ws, size_t ws_size,
                              hipStream_t stream) {
    const float* features = (const float*)d_in[0];
    const float* theta    = (const float*)d_in[1];
    const float* wbias    = (const float*)d_in[2];
    const int*   nbh      = (const int*)  d_in[3];
    const float* pos      = (const float*)d_in[4];
    const float* bias     = (const float*)d_in[5];
    float* out = (float*)d_out;

    // ---- Path D: index buckets + ftfb16 (~52.3 MiB, 3 nodes) ----
    {
        const size_t ftfb_bytes   = ((size_t)B_ * N_ << 6) * sizeof(uint2);  // 32 MiB
        const size_t bucket_bytes = (size_t)B_ * N_ * CAP_ * sizeof(int);    // 4 MiB
        const size_t cursor_bytes = (size_t)B_ * N_ * sizeof(int);           // 256 KiB
        const size_t ws2_bytes    = ((size_t)B_ * N_ << 6) * sizeof(float);  // 16 MiB

        size_t off = 0;
        uint2* ftfb   = (uint2*)((char*)d_ws + off); off += ftfb_bytes;
        int*   bucket = (int*)  ((char*)d_ws + off); off += bucket_bytes;
        int*   cursor = (int*)  ((char*)d_ws + off); off += cursor_bytes;
        float* ws2    = (float*)((char*)d_ws + off); off += ws2_bytes;

        if (ws_size >= off) {
            // one memset covers cursor + ws2 (contiguous)
            hipMemsetAsync(cursor, 0, cursor_bytes + ws2_bytes, stream);
            fc_contribD<<<B_ * (N_ / 128), 512, 0, stream>>>(features, theta, wbias,
                                                             nbh, pos, cursor,
                                                             bucket, ftfb, ws2);
            fc_gatherD<<<B_ * (N_ / 64), 512, 0, stream>>>(ftfb, bucket, cursor,
                                                           ws2, pos, bias, out);
            return;
        }
    }

    // ---- Path C: atomic fallback (16 MiB) ----
    {
        float* ws = (float*)d_ws;
        const size_t ws_bytes = (size_t)B_ * N_ * COUT_ * sizeof(float);
        hipMemsetAsync(ws, 0, ws_bytes, stream);
        flexconv_main<<<B_ * (N_ / 128), 256, 0, stream>>>(features, theta, wbias,
                                                           nbh, pos, ws);
        flexconv_finish<<<B_ * (N_ / 64), 256, 0, stream>>>(ws, bias, out);
    }
}